// Round 1
// baseline (590.615 us; speedup 1.0000x reference)
//
#include <hip/hip_runtime.h>

#define EPS 1e-3f

typedef _Float16 f16;
typedef _Float16 f16x8 __attribute__((ext_vector_type(8)));
typedef _Float16 f16x4 __attribute__((ext_vector_type(4)));
typedef float f32x4 __attribute__((ext_vector_type(4)));

// problem sizes
constexpr int Bn = 8, C = 512, C8 = 64;
constexpr int N = 16384;          // Z*H*W
constexpr int M = Bn * N;         // 131072 rows

// ws layout (bytes), all 16B-aligned
constexpr size_t OFF_WHI  = 0;                                  // f16 [192][512]  folded qkv weights (hi), n-major
constexpr size_t OFF_WLO  = 196608;                             // f16 [128][512]  folded q,k weights (lo*2048)
constexpr size_t OFF_BQKV = 327680;                             // f32 [192]       folded qkv bias
constexpr size_t OFF_WPT  = 328704;                             // f16 [512][64]   folded proj weight, transposed
constexpr size_t OFF_BOUT = 394240;                             // f32 [512]       folded out bias
constexpr size_t OFF_QK   = 396288;                             // f16 [131072][128] q|k ; later overlaid by attn f16[8][64][16384]
constexpr size_t OFF_V    = OFF_QK + (size_t)M * 128 * 2;       // f16 [131072][64]
constexpr size_t OFF_PART = OFF_V + (size_t)M * 64 * 2;         // f32 [8][16][64][64] gram partials
constexpr size_t OFF_BT   = OFF_PART + (size_t)8*16*4096*4;     // f16 [8][64][64]  beta^T:  bt[i][m] = beta[m][i]

// ---------------- K0: fold BN into weights ----------------
__global__ __launch_bounds__(256) void k0_fold(
    const float* g1, const float* be1, const float* mu1, const float* va1,
    const float* wq, const float* bq, const float* wk, const float* bk,
    const float* wv, const float* bv, const float* wp, const float* bp,
    const float* g2, const float* be2, const float* mu2, const float* va2,
    char* ws)
{
  f16* whi = (f16*)(ws + OFF_WHI);
  f16* wlo = (f16*)(ws + OFF_WLO);
  float* bqkv = (float*)(ws + OFF_BQKV);
  f16* wpt = (f16*)(ws + OFF_WPT);
  float* bout = (float*)(ws + OFF_BOUT);
  __shared__ float red[256];
  int blk = blockIdx.x, t = threadIdx.x;
  if (blk < 192) {
    const float* w; const float* bb; int col;
    if (blk < 64)       { w = wq; bb = bq; col = blk; }
    else if (blk < 128) { w = wk; bb = bk; col = blk - 64; }
    else                { w = wv; bb = bv; col = blk - 128; }
    float part = 0.f;
    for (int c = t; c < 512; c += 256) {
      float a1 = g1[c] * rsqrtf(va1[c] + EPS);
      float d1 = be1[c] - mu1[c] * a1;
      float wval = w[c * 64 + col];
      float fw = a1 * wval;
      f16 hi = (f16)fw;
      whi[blk * 512 + c] = hi;
      if (blk < 128) wlo[blk * 512 + c] = (f16)((fw - (float)hi) * 2048.0f);
      part += d1 * wval;
    }
    red[t] = part; __syncthreads();
    for (int s = 128; s > 0; s >>= 1) { if (t < s) red[t] += red[t + s]; __syncthreads(); }
    if (t == 0) bqkv[blk] = red[0] + bb[col];
  } else {
    int co = blk - 192;  // 0..511
    float a2 = g2[co] * rsqrtf(va2[co] + EPS);
    if (t < 64) wpt[co * 64 + t] = (f16)(wp[t * 512 + co] * a2);
    if (t == 0) bout[co] = (bp[co] - mu2[co]) * a2 + be2[co];
  }
}

// ---------------- K1: fused BN1 + QKV GEMM ----------------
// grid 2048, block 256 (4 waves). Tile: 64(M) x 192(N), K=512 in 16 steps of 32.
// wave w owns n-tiles {w, w+4, w+8}: two q/k tiles (2-pass hi+lo) + one v tile.
__global__ __launch_bounds__(256, 2) void k1_qkv(const float* __restrict__ x, char* __restrict__ ws)
{
  const f16* whi = (const f16*)(ws + OFF_WHI);
  const f16* wlo = (const f16*)(ws + OFF_WLO);
  const float* bqkv = (const float*)(ws + OFF_BQKV);
  f16* qkbuf = (f16*)(ws + OFF_QK);
  f16* vbuf  = (f16*)(ws + OFF_V);

  __shared__ f16 xs[64 * 40];   // x tile as fp16, row stride 40 (16B-aligned frag reads, 2-way banks)

  int t = threadIdx.x;
  int wave = t >> 6, lane = t & 63;
  int m0 = blockIdx.x * 64;

  int nt0 = wave, nt1 = wave + 4, nt2 = wave + 8;

  f32x4 acc_h[4][2], acc_l[4][2], acc_v[4];
  for (int i = 0; i < 4; i++) {
    for (int j = 0; j < 2; j++) { acc_h[i][j] = (f32x4){0.f,0.f,0.f,0.f}; acc_l[i][j] = (f32x4){0.f,0.f,0.f,0.f}; }
    acc_v[i] = (f32x4){0.f,0.f,0.f,0.f};
  }

  // A staging: thread loads 2 float4 (rows t>>3 and +32, cols (t&7)*4)
  int arow = t >> 3;
  int acol = (t & 7) * 4;
  const float* xg = x + (size_t)(m0 + arow) * 512 + acol;

  int bn0 = nt0 * 16 + (lane & 15);
  int bn1 = nt1 * 16 + (lane & 15);
  int bn2 = nt2 * 16 + (lane & 15);
  int bko = (lane >> 4) * 8;

  // prefetch kc=0
  f32x4 a0 = *(const f32x4*)(xg);
  f32x4 a1 = *(const f32x4*)(xg + 32 * 512);
  f16x8 b0h = *(const f16x8*)(whi + bn0 * 512 + bko);
  f16x8 b1h = *(const f16x8*)(whi + bn1 * 512 + bko);
  f16x8 b2h = *(const f16x8*)(whi + bn2 * 512 + bko);
  f16x8 b0l = *(const f16x8*)(wlo + bn0 * 512 + bko);
  f16x8 b1l = *(const f16x8*)(wlo + bn1 * 512 + bko);

  for (int kc = 0; kc < 16; kc++) {
    f16x4 h0, h1;
    for (int e = 0; e < 4; e++) { h0[e] = (f16)a0[e]; h1[e] = (f16)a1[e]; }
    *(f16x4*)&xs[arow * 40 + acol] = h0;
    *(f16x4*)&xs[(arow + 32) * 40 + acol] = h1;
    __syncthreads();

    f16x8 B0h = b0h, B1h = b1h, B2h = b2h, B0l = b0l, B1l = b1l;
    if (kc < 15) {
      const float* xg2 = xg + (kc + 1) * 32;
      a0 = *(const f32x4*)(xg2);
      a1 = *(const f32x4*)(xg2 + 32 * 512);
      int ko = (kc + 1) * 32 + bko;
      b0h = *(const f16x8*)(whi + bn0 * 512 + ko);
      b1h = *(const f16x8*)(whi + bn1 * 512 + ko);
      b2h = *(const f16x8*)(whi + bn2 * 512 + ko);
      b0l = *(const f16x8*)(wlo + bn0 * 512 + ko);
      b1l = *(const f16x8*)(wlo + bn1 * 512 + ko);
    }

    int aoff = (lane & 15) * 40 + (lane >> 4) * 8;
    for (int mt = 0; mt < 4; mt++) {
      f16x8 af = *(const f16x8*)&xs[mt * 16 * 40 + aoff];
      acc_h[mt][0] = __builtin_amdgcn_mfma_f32_16x16x32_f16(af, B0h, acc_h[mt][0], 0, 0, 0);
      acc_h[mt][1] = __builtin_amdgcn_mfma_f32_16x16x32_f16(af, B1h, acc_h[mt][1], 0, 0, 0);
      acc_l[mt][0] = __builtin_amdgcn_mfma_f32_16x16x32_f16(af, B0l, acc_l[mt][0], 0, 0, 0);
      acc_l[mt][1] = __builtin_amdgcn_mfma_f32_16x16x32_f16(af, B1l, acc_l[mt][1], 0, 0, 0);
      acc_v[mt]    = __builtin_amdgcn_mfma_f32_16x16x32_f16(af, B2h, acc_v[mt],    0, 0, 0);
    }
    __syncthreads();
  }

  // epilogue: recombine hi + lo/2048, add folded bias, store fp16
  const float inv2048 = 1.0f / 2048.0f;
  int colA = nt0 * 16 + (lane & 15);
  int colB = nt1 * 16 + (lane & 15);
  int colV = nt2 * 16 + (lane & 15);      // 128..191
  float bA = bqkv[colA], bB = bqkv[colB], bV = bqkv[colV];
  int rbase = m0 + (lane >> 4) * 4;
  for (int mt = 0; mt < 4; mt++) {
    for (int r = 0; r < 4; r++) {
      size_t row = (size_t)(rbase + mt * 16 + r);
      qkbuf[row * 128 + colA] = (f16)(acc_h[mt][0][r] + acc_l[mt][0][r] * inv2048 + bA);
      qkbuf[row * 128 + colB] = (f16)(acc_h[mt][1][r] + acc_l[mt][1][r] * inv2048 + bB);
      vbuf[row * 64 + (colV - 128)] = (f16)(acc_v[mt][r] + bV);
    }
  }
}

// ---------------- K2a: gram partials s[b,i,j] = sum_n q[n,i] k[n,j] ----------------
// grid 128 = 8 batches x 16 chunks of 1024 n. Per block: 64x64 output partial.
__global__ __launch_bounds__(256) void k2a_gram(char* __restrict__ ws)
{
  const f16* qkbuf = (const f16*)(ws + OFF_QK);
  float* part = (float*)(ws + OFF_PART);
  __shared__ f16 tlds[128 * 40];   // transposed [col][n_local], stride 40
  int t = threadIdx.x, wave = t >> 6, lane = t & 63;
  int b = blockIdx.x >> 4, ch = blockIdx.x & 15;
  size_t base = (size_t)(b * 16384 + ch * 1024) * 128;

  f32x4 acc[4];
  for (int i = 0; i < 4; i++) acc[i] = (f32x4){0.f,0.f,0.f,0.f};

  int lrow = t >> 3;           // 0..31
  int lcol = (t & 7) * 16;     // 0..112

  for (int it = 0; it < 32; it++) {
    const f16* src = qkbuf + base + (size_t)(it * 32 + lrow) * 128 + lcol;
    f16x8 v0 = *(const f16x8*)(src);
    f16x8 v1 = *(const f16x8*)(src + 8);
    __syncthreads();
    for (int e = 0; e < 8; e++) tlds[(lcol + e) * 40 + lrow] = v0[e];
    for (int e = 0; e < 8; e++) tlds[(lcol + 8 + e) * 40 + lrow] = v1[e];
    __syncthreads();
    int koff = (lane >> 4) * 8;
    f16x8 bf = *(const f16x8*)&tlds[(64 + wave * 16 + (lane & 15)) * 40 + koff];
    for (int itile = 0; itile < 4; itile++) {
      f16x8 af = *(const f16x8*)&tlds[(itile * 16 + (lane & 15)) * 40 + koff];
      acc[itile] = __builtin_amdgcn_mfma_f32_16x16x32_f16(af, bf, acc[itile], 0, 0, 0);
    }
  }
  float* dst = part + (size_t)blockIdx.x * 4096;
  int j = wave * 16 + (lane & 15);
  for (int itile = 0; itile < 4; itile++)
    for (int r = 0; r < 4; r++) {
      int i = itile * 16 + (lane >> 4) * 4 + r;
      dst[i * 64 + j] = acc[itile][r];
    }
}

// ---------------- K2b: reduce partials + softmax -> beta^T (fp16) ----------------
__global__ __launch_bounds__(256) void k2b_softmax(char* __restrict__ ws)
{
  const float* part = (const float*)(ws + OFF_PART);
  f16* bt = (f16*)(ws + OFF_BT);
  __shared__ float s[4096];
  int b = blockIdx.x, t = threadIdx.x;
  for (int cell = t; cell < 4096; cell += 256) {
    float sum = 0.f;
    for (int ch = 0; ch < 16; ch++) sum += part[(size_t)(b * 16 + ch) * 4096 + cell];
    s[cell] = sum;
  }
  __syncthreads();
  if (t < 64) {
    float mx = -1e30f;
    for (int j = 0; j < 64; j++) mx = fmaxf(mx, s[t * 64 + j]);
    float e[64]; float den = 0.f;
    for (int j = 0; j < 64; j++) { e[j] = __expf(s[t * 64 + j] - mx); den += e[j]; }
    float inv = 1.0f / den;
    // beta[m=t][j] -> bt[j][m]
    for (int j = 0; j < 64; j++) bt[(size_t)b * 4096 + j * 64 + t] = (f16)(e[j] * inv);
  }
}

// ---------------- K3: attn[b,i,j] = sum_m beta[m,i] v[j,m] ----------------
// grid 512 = 8 b x 64 j-chunks(256). attn stored (64 x 16384) f16, overlays qk buffer.
__global__ __launch_bounds__(256) void k3_attn(char* __restrict__ ws)
{
  const f16* vbuf = (const f16*)(ws + OFF_V);
  const f16* bt = (const f16*)(ws + OFF_BT);
  f16* attn = (f16*)(ws + OFF_QK);
  int t = threadIdx.x, wave = t >> 6, lane = t & 63;
  int b = blockIdx.x >> 6, jc = blockIdx.x & 63;
  int j0 = jc * 256 + wave * 64;

  f32x4 acc[4][4];
  for (int i = 0; i < 4; i++) for (int j = 0; j < 4; j++) acc[i][j] = (f32x4){0.f,0.f,0.f,0.f};

  int koff = (lane >> 4) * 8;
  for (int km = 0; km < 2; km++) {
    f16x8 af[4], bf[4];
    for (int it = 0; it < 4; it++)
      af[it] = *(const f16x8*)(bt + (size_t)b * 4096 + (it * 16 + (lane & 15)) * 64 + km * 32 + koff);
    for (int jt = 0; jt < 4; jt++)
      bf[jt] = *(const f16x8*)(vbuf + (size_t)(b * 16384 + j0 + jt * 16 + (lane & 15)) * 64 + km * 32 + koff);
    for (int it = 0; it < 4; it++)
      for (int jt = 0; jt < 4; jt++)
        acc[it][jt] = __builtin_amdgcn_mfma_f32_16x16x32_f16(af[it], bf[jt], acc[it][jt], 0, 0, 0);
  }
  size_t abase = (size_t)b * 1048576;
  for (int it = 0; it < 4; it++)
    for (int jt = 0; jt < 4; jt++)
      for (int r = 0; r < 4; r++) {
        int i = it * 16 + (lane >> 4) * 4 + r;
        int j = j0 + jt * 16 + (lane & 15);
        attn[abase + (size_t)i * 16384 + j] = (f16)acc[it][jt][r];
      }
}

// ---------------- K4: projection + BN2 ----------------
// out[row, c] = sum_d attn_flat[row*64+d] * wpT[c][d] + bout[c]
// grid 2048 (64 rows each), block 256: wave w covers c-range [w*128, w*128+128)
__global__ __launch_bounds__(256, 2) void k4_proj(const char* __restrict__ ws, float* __restrict__ out)
{
  const f16* attn = (const f16*)(ws + OFF_QK);
  const f16* wpt = (const f16*)(ws + OFF_WPT);
  const float* bout = (const float*)(ws + OFF_BOUT);
  int t = threadIdx.x, wave = t >> 6, lane = t & 63;
  int m0 = blockIdx.x * 64;
  int c0 = wave * 128;

  f32x4 acc[4][8];
  for (int i = 0; i < 4; i++) for (int j = 0; j < 8; j++) acc[i][j] = (f32x4){0.f,0.f,0.f,0.f};
  int koff = (lane >> 4) * 8;
  for (int km = 0; km < 2; km++) {
    f16x8 af[4], bf[8];
    for (int mt = 0; mt < 4; mt++)
      af[mt] = *(const f16x8*)(attn + (size_t)(m0 + mt * 16 + (lane & 15)) * 64 + km * 32 + koff);
    for (int nt = 0; nt < 8; nt++)
      bf[nt] = *(const f16x8*)(wpt + (size_t)(c0 + nt * 16 + (lane & 15)) * 64 + km * 32 + koff);
    for (int mt = 0; mt < 4; mt++)
      for (int nt = 0; nt < 8; nt++)
        acc[mt][nt] = __builtin_amdgcn_mfma_f32_16x16x32_f16(af[mt], bf[nt], acc[mt][nt], 0, 0, 0);
  }
  for (int nt = 0; nt < 8; nt++) {
    int c = c0 + nt * 16 + (lane & 15);
    float bc = bout[c];
    for (int mt = 0; mt < 4; mt++)
      for (int r = 0; r < 4; r++) {
        int row = m0 + mt * 16 + (lane >> 4) * 4 + r;
        out[(size_t)row * 512 + c] = acc[mt][nt][r] + bc;
      }
  }
}

extern "C" void kernel_launch(void* const* d_in, const int* in_sizes, int n_in,
                              void* d_out, int out_size, void* d_ws, size_t ws_size,
                              hipStream_t stream)
{
  const float* x   = (const float*)d_in[0];
  const float* g1  = (const float*)d_in[1];
  const float* be1 = (const float*)d_in[2];
  const float* mu1 = (const float*)d_in[3];
  const float* va1 = (const float*)d_in[4];
  const float* wq  = (const float*)d_in[5];
  const float* bq  = (const float*)d_in[6];
  const float* wk  = (const float*)d_in[7];
  const float* bk  = (const float*)d_in[8];
  const float* wv  = (const float*)d_in[9];
  const float* bv  = (const float*)d_in[10];
  const float* wp  = (const float*)d_in[11];
  const float* bp  = (const float*)d_in[12];
  const float* g2  = (const float*)d_in[13];
  const float* be2 = (const float*)d_in[14];
  const float* mu2 = (const float*)d_in[15];
  const float* va2 = (const float*)d_in[16];
  char* ws = (char*)d_ws;
  float* out = (float*)d_out;

  k0_fold<<<dim3(704), dim3(256), 0, stream>>>(g1, be1, mu1, va1, wq, bq, wk, bk,
                                               wv, bv, wp, bp, g2, be2, mu2, va2, ws);
  k1_qkv<<<dim3(2048), dim3(256), 0, stream>>>(x, ws);
  k2a_gram<<<dim3(128), dim3(256), 0, stream>>>(ws);
  k2b_softmax<<<dim3(8), dim3(256), 0, stream>>>(ws);
  k3_attn<<<dim3(512), dim3(256), 0, stream>>>(ws);
  k4_proj<<<dim3(2048), dim3(256), 0, stream>>>(ws, out);
}

// Round 2
// 578.852 us; speedup vs baseline: 1.0203x; 1.0203x over previous
//
#include <hip/hip_runtime.h>

#define EPS 1e-3f

typedef _Float16 f16;
typedef _Float16 f16x8 __attribute__((ext_vector_type(8)));
typedef _Float16 f16x4 __attribute__((ext_vector_type(4)));
typedef float f32x4 __attribute__((ext_vector_type(4)));

// problem sizes
constexpr int Bn = 8, C = 512, C8 = 64;
constexpr int N = 16384;          // Z*H*W
constexpr int M = Bn * N;         // 131072 rows

// ws layout (bytes), 16B-aligned
constexpr size_t OFF_WHI  = 0;                              // f16 [192][512] folded qkv weights (hi)
constexpr size_t OFF_WLO  = 196608;                         // f16 [128][512] folded q,k weights (lo*2048)
constexpr size_t OFF_BQKV = 327680;                         // f32 [192]
constexpr size_t OFF_WPT  = 328704;                         // f16 [512][64]  folded proj weight^T
constexpr size_t OFF_BOUT = 394240;                         // f32 [512]
constexpr size_t OFF_QK   = 396288;                         // f16 [131072][128] q|k
constexpr size_t OFF_V    = OFF_QK + (size_t)M * 128 * 2;   // f16 [131072][64]
constexpr size_t OFF_S    = OFF_V + (size_t)M * 64 * 2;     // f32 [8][4096] gram scores (atomic-accumulated)
constexpr size_t OFF_BT   = OFF_S + (size_t)8 * 4096 * 4;   // f16 [8][64][64] beta^T: bt[i][m]=beta[m][i]

// ---------------- K0: fold BN into weights + zero score buffer ----------------
__global__ __launch_bounds__(256) void k0_fold(
    const float* g1, const float* be1, const float* mu1, const float* va1,
    const float* wq, const float* bq, const float* wk, const float* bk,
    const float* wv, const float* bv, const float* wp, const float* bp,
    const float* g2, const float* be2, const float* mu2, const float* va2,
    char* ws)
{
  f16* whi = (f16*)(ws + OFF_WHI);
  f16* wlo = (f16*)(ws + OFF_WLO);
  float* bqkv = (float*)(ws + OFF_BQKV);
  f16* wpt = (f16*)(ws + OFF_WPT);
  float* bout = (float*)(ws + OFF_BOUT);
  float* sbuf = (float*)(ws + OFF_S);
  __shared__ float red[256];
  int blk = blockIdx.x, t = threadIdx.x;
  if (blk < 192) {
    const float* w; const float* bb; int col;
    if (blk < 64)       { w = wq; bb = bq; col = blk; }
    else if (blk < 128) { w = wk; bb = bk; col = blk - 64; }
    else                { w = wv; bb = bv; col = blk - 128; }
    float part = 0.f;
    for (int c = t; c < 512; c += 256) {
      float a1 = g1[c] * rsqrtf(va1[c] + EPS);
      float d1 = be1[c] - mu1[c] * a1;
      float wval = w[c * 64 + col];
      float fw = a1 * wval;
      f16 hi = (f16)fw;
      whi[blk * 512 + c] = hi;
      if (blk < 128) wlo[blk * 512 + c] = (f16)((fw - (float)hi) * 2048.0f);
      part += d1 * wval;
    }
    red[t] = part; __syncthreads();
    for (int s = 128; s > 0; s >>= 1) { if (t < s) red[t] += red[t + s]; __syncthreads(); }
    if (t == 0) bqkv[blk] = red[0] + bb[col];
  } else {
    int co = blk - 192;  // 0..511
    float a2 = g2[co] * rsqrtf(va2[co] + EPS);
    if (t < 64) wpt[co * 64 + t] = (f16)(wp[t * 512 + co] * a2);
    if (t == 0) bout[co] = (bp[co] - mu2[co]) * a2 + be2[co];
    if (t < 64) sbuf[co * 64 + t] = 0.0f;   // zero 8x4096 score buffer
  }
}

// ---------------- K1: fused BN1 + QKV GEMM ----------------
// Double-buffered LDS, ONE barrier per 64-wide k-chunk (8 total vs 32 before).
// A-prefetch issued immediately after the barrier -> barrier vmcnt-drain stall
// shrinks from ~900 to ~400 cyc. grid 2048 x 256thr, 64(M)x192(N) tile.
__global__ __launch_bounds__(256, 2) void k1_qkv(const float* __restrict__ x, char* __restrict__ ws)
{
  const f16* whi = (const f16*)(ws + OFF_WHI);
  const f16* wlo = (const f16*)(ws + OFF_WLO);
  const float* bqkv = (const float*)(ws + OFF_BQKV);
  f16* qkbuf = (f16*)(ws + OFF_QK);
  f16* vbuf  = (f16*)(ws + OFF_V);

  __shared__ f16 xs[2][64 * 72];   // 64 rows x 64 cols, stride 72 (16B-aligned b128 reads)

  int t = threadIdx.x;
  int wave = t >> 6, lane = t & 63;
  int m0 = blockIdx.x * 64;

  // staging: thread -> row t>>2, cols (t&3)*4 + {0,16,32,48}; lanes 0..3 = 64B contiguous
  int srow = t >> 2, scol = (t & 3) * 4;
  const float* xg = x + (size_t)(m0 + srow) * 512 + scol;

  int bn0 = wave * 16 + (lane & 15);   // q col tile
  int bn1 = bn0 + 64;                  // k col tile
  int bn2 = bn0 + 128;                 // v col tile
  int klane = (lane >> 4) * 8;

  f32x4 acc_h[4][2], acc_l[4][2], acc_v[4];
  for (int i = 0; i < 4; i++) {
    for (int j = 0; j < 2; j++) { acc_h[i][j] = (f32x4){0.f,0.f,0.f,0.f}; acc_l[i][j] = (f32x4){0.f,0.f,0.f,0.f}; }
    acc_v[i] = (f32x4){0.f,0.f,0.f,0.f};
  }

  f32x4 a0 = *(const f32x4*)(xg);
  f32x4 a1 = *(const f32x4*)(xg + 16);
  f32x4 a2 = *(const f32x4*)(xg + 32);
  f32x4 a3 = *(const f32x4*)(xg + 48);

  for (int iter = 0; iter < 8; iter++) {
    f16* xb = &xs[iter & 1][0];
    {
      f16x4 h0, h1, h2, h3;
      for (int e = 0; e < 4; e++) { h0[e]=(f16)a0[e]; h1[e]=(f16)a1[e]; h2[e]=(f16)a2[e]; h3[e]=(f16)a3[e]; }
      *(f16x4*)&xb[srow * 72 + scol     ] = h0;
      *(f16x4*)&xb[srow * 72 + scol + 16] = h1;
      *(f16x4*)&xb[srow * 72 + scol + 32] = h2;
      *(f16x4*)&xb[srow * 72 + scol + 48] = h3;
    }
    __syncthreads();
    if (iter < 7) {
      const float* xi = xg + (iter + 1) * 64;
      a0 = *(const f32x4*)(xi);
      a1 = *(const f32x4*)(xi + 16);
      a2 = *(const f32x4*)(xi + 32);
      a3 = *(const f32x4*)(xi + 48);
    }
    for (int ks = 0; ks < 2; ks++) {
      int kg = iter * 64 + ks * 32 + klane;
      f16x8 b0h = *(const f16x8*)(whi + bn0 * 512 + kg);
      f16x8 b1h = *(const f16x8*)(whi + bn1 * 512 + kg);
      f16x8 b2h = *(const f16x8*)(whi + bn2 * 512 + kg);
      f16x8 b0l = *(const f16x8*)(wlo + bn0 * 512 + kg);
      f16x8 b1l = *(const f16x8*)(wlo + bn1 * 512 + kg);
      int aoff = (lane & 15) * 72 + ks * 32 + klane;
      for (int mt = 0; mt < 4; mt++) {
        f16x8 af = *(const f16x8*)&xb[mt * 16 * 72 + aoff];
        acc_h[mt][0] = __builtin_amdgcn_mfma_f32_16x16x32_f16(af, b0h, acc_h[mt][0], 0, 0, 0);
        acc_h[mt][1] = __builtin_amdgcn_mfma_f32_16x16x32_f16(af, b1h, acc_h[mt][1], 0, 0, 0);
        acc_l[mt][0] = __builtin_amdgcn_mfma_f32_16x16x32_f16(af, b0l, acc_l[mt][0], 0, 0, 0);
        acc_l[mt][1] = __builtin_amdgcn_mfma_f32_16x16x32_f16(af, b1l, acc_l[mt][1], 0, 0, 0);
        acc_v[mt]    = __builtin_amdgcn_mfma_f32_16x16x32_f16(af, b2h, acc_v[mt],    0, 0, 0);
      }
    }
  }

  const float inv2048 = 1.0f / 2048.0f;
  int colA = bn0, colB = bn1, colV = bn0;
  float bA = bqkv[colA], bB = bqkv[colB], bV = bqkv[bn2];
  int rbase = m0 + (lane >> 4) * 4;
  for (int mt = 0; mt < 4; mt++) {
    for (int r = 0; r < 4; r++) {
      size_t row = (size_t)(rbase + mt * 16 + r);
      qkbuf[row * 128 + colA] = (f16)(acc_h[mt][0][r] + acc_l[mt][0][r] * inv2048 + bA);
      qkbuf[row * 128 + colB] = (f16)(acc_h[mt][1][r] + acc_l[mt][1][r] * inv2048 + bB);
      vbuf[row * 64 + colV]   = (f16)(acc_v[mt][r] + bV);
    }
  }
}

// ---------------- K2a: gram s[b,i,j] = sum_n q[n,i] k[n,j] ----------------
// LDS-free, barrier-free: fragments gathered straight from L2/L3-resident qk
// buffer (u16 loads; lanes 0..15 are 32B-contiguous). 512 blocks (8b x 64 chunks
// of 256 n). Partials accumulated with atomicAdd into s[8][4096].
__global__ __launch_bounds__(256) void k2a_gram(char* __restrict__ ws)
{
  const f16* qk = (const f16*)(ws + OFF_QK);
  float* sbuf = (float*)(ws + OFF_S);
  int t = threadIdx.x, wave = t >> 6, lane = t & 63;
  int b = blockIdx.x >> 6, ch = blockIdx.x & 63;
  int n0 = b * 16384 + ch * 256;

  f32x4 acc[4];
  for (int i = 0; i < 4; i++) acc[i] = (f32x4){0.f,0.f,0.f,0.f};

  int li = lane & 15;
  int jc = 64 + wave * 16 + li;

  for (int it = 0; it < 8; it++) {
    const f16* p = qk + (size_t)(n0 + it * 32 + (lane >> 4) * 8) * 128;
    f16x8 af0, af1, af2, af3, bf;
#pragma unroll
    for (int j = 0; j < 8; j++) {
      const f16* pr = p + j * 128;
      af0[j] = pr[li];
      af1[j] = pr[16 + li];
      af2[j] = pr[32 + li];
      af3[j] = pr[48 + li];
      bf[j]  = pr[jc];
    }
    acc[0] = __builtin_amdgcn_mfma_f32_16x16x32_f16(af0, bf, acc[0], 0, 0, 0);
    acc[1] = __builtin_amdgcn_mfma_f32_16x16x32_f16(af1, bf, acc[1], 0, 0, 0);
    acc[2] = __builtin_amdgcn_mfma_f32_16x16x32_f16(af2, bf, acc[2], 0, 0, 0);
    acc[3] = __builtin_amdgcn_mfma_f32_16x16x32_f16(af3, bf, acc[3], 0, 0, 0);
  }
  int j = wave * 16 + li;
  for (int itile = 0; itile < 4; itile++)
    for (int r = 0; r < 4; r++) {
      int i = itile * 16 + (lane >> 4) * 4 + r;
      atomicAdd(&sbuf[(size_t)b * 4096 + i * 64 + j], acc[itile][r]);
    }
}

// ---------------- K2b: softmax -> beta^T (fp16) ----------------
__global__ __launch_bounds__(256) void k2b_softmax(char* __restrict__ ws)
{
  const float* sbuf = (const float*)(ws + OFF_S);
  f16* bt = (f16*)(ws + OFF_BT);
  int b = blockIdx.x, t = threadIdx.x;
  if (t < 64) {
    const float* srow = sbuf + (size_t)b * 4096 + t * 64;
    float mx = -1e30f;
    for (int j = 0; j < 64; j++) mx = fmaxf(mx, srow[j]);
    float e[64]; float den = 0.f;
    for (int j = 0; j < 64; j++) { e[j] = __expf(srow[j] - mx); den += e[j]; }
    float inv = 1.0f / den;
    // beta[m=t][j] -> bt[j][m]
    for (int j = 0; j < 64; j++) bt[(size_t)b * 4096 + j * 64 + t] = (f16)(e[j] * inv);
  }
}

// ---------------- K34: fused attn + projection + BN2 ----------------
// grid 1024 = 8b x 128 j-chunks(128). Phase1: attn tile (64i x 128j) = beta^T.v^T
// -> the flat reshape makes this exactly 128 contiguous pos-rows x 64 d ->
// XOR-swizzled LDS (conflict-free b16 writes, aligned b128 reads). Phase2:
// projection GEMM 128x512x64 + bias, streamed to out.
__device__ __forceinline__ int at_idx(int row, int d) {
  int dd = (d >> 1) ^ (((row >> 3) & 3) << 3);
  return row * 64 + dd * 2 + (d & 1);
}

__global__ __launch_bounds__(256, 2) void k34_attn_proj(char* __restrict__ ws, float* __restrict__ out)
{
  const f16* vbuf = (const f16*)(ws + OFF_V);
  const f16* bt = (const f16*)(ws + OFF_BT);
  const f16* wpt = (const f16*)(ws + OFF_WPT);
  const float* bout = (const float*)(ws + OFF_BOUT);
  __shared__ f16 at[128 * 64];   // 16 KB, xor-swizzled

  int t = threadIdx.x, wave = t >> 6, lane = t & 63;
  int b = blockIdx.x >> 7, jc = blockIdx.x & 127;
  int li = lane & 15;
  int klane = (lane >> 4) * 8;

  // ---- phase 1: attn[i, j] for i=0..63, j = jc*128 .. +127 (wave owns 32 j) ----
  f32x4 acc[4][2];
  for (int i = 0; i < 4; i++) for (int j = 0; j < 2; j++) acc[i][j] = (f32x4){0.f,0.f,0.f,0.f};

  for (int km = 0; km < 2; km++) {
    f16x8 af[4], bf[2];
    for (int it = 0; it < 4; it++)
      af[it] = *(const f16x8*)(bt + (size_t)b * 4096 + (it * 16 + li) * 64 + km * 32 + klane);
    for (int jt = 0; jt < 2; jt++) {
      int jrow = jc * 128 + wave * 32 + jt * 16 + li;
      bf[jt] = *(const f16x8*)(vbuf + (size_t)(b * 16384 + jrow) * 64 + km * 32 + klane);
    }
    for (int it = 0; it < 4; it++)
      for (int jt = 0; jt < 2; jt++)
        acc[it][jt] = __builtin_amdgcn_mfma_f32_16x16x32_f16(af[it], bf[jt], acc[it][jt], 0, 0, 0);
  }
  // scatter to LDS: row_local = i*2 + (wave>>1), d = (wave&1)*32 + jt*16 + li
  for (int it = 0; it < 4; it++)
    for (int jt = 0; jt < 2; jt++)
      for (int r = 0; r < 4; r++) {
        int i = it * 16 + (lane >> 4) * 4 + r;
        int d = (wave & 1) * 32 + jt * 16 + li;
        at[at_idx(i * 2 + (wave >> 1), d)] = (f16)acc[it][jt][r];
      }
  __syncthreads();

  // ---- phase 2: out[pos, c] = sum_d attn[pos, d] * wpt[c][d] + bout[c] ----
  // wave owns rows wave*32 .. +31 (2 m-tiles); c in 8 strips of 64.
  f16x8 paf[2][2];
  for (int mt = 0; mt < 2; mt++)
    for (int km = 0; km < 2; km++) {
      int row = wave * 32 + mt * 16 + li;
      int d = km * 32 + klane;
      paf[mt][km] = *(const f16x8*)&at[row * 64 + ((((d >> 1) ^ (((row >> 3) & 3) << 3))) << 1)];
    }
  size_t obase = (size_t)b * 16384 * 512;
  for (int strip = 0; strip < 8; strip++) {
    int c0 = strip * 64;
    f16x8 pbf[2][4];
    for (int nt = 0; nt < 4; nt++)
      for (int km = 0; km < 2; km++)
        pbf[km][nt] = *(const f16x8*)(wpt + (size_t)(c0 + nt * 16 + li) * 64 + km * 32 + klane);
    f32x4 pac[2][4];
    for (int mt = 0; mt < 2; mt++) for (int nt = 0; nt < 4; nt++) pac[mt][nt] = (f32x4){0.f,0.f,0.f,0.f};
    for (int km = 0; km < 2; km++)
      for (int mt = 0; mt < 2; mt++)
        for (int nt = 0; nt < 4; nt++)
          pac[mt][nt] = __builtin_amdgcn_mfma_f32_16x16x32_f16(paf[mt][km], pbf[km][nt], pac[mt][nt], 0, 0, 0);
    for (int nt = 0; nt < 4; nt++) {
      int c = c0 + nt * 16 + li;
      float bc = bout[c];
      for (int mt = 0; mt < 2; mt++)
        for (int r = 0; r < 4; r++) {
          int rl = wave * 32 + mt * 16 + (lane >> 4) * 4 + r;
          int pos = (rl >> 1) * 256 + jc * 2 + (rl & 1);
          out[obase + (size_t)pos * 512 + c] = pac[mt][nt][r] + bc;
        }
    }
  }
}

extern "C" void kernel_launch(void* const* d_in, const int* in_sizes, int n_in,
                              void* d_out, int out_size, void* d_ws, size_t ws_size,
                              hipStream_t stream)
{
  const float* x   = (const float*)d_in[0];
  const float* g1  = (const float*)d_in[1];
  const float* be1 = (const float*)d_in[2];
  const float* mu1 = (const float*)d_in[3];
  const float* va1 = (const float*)d_in[4];
  const float* wq  = (const float*)d_in[5];
  const float* bq  = (const float*)d_in[6];
  const float* wk  = (const float*)d_in[7];
  const float* bk  = (const float*)d_in[8];
  const float* wv  = (const float*)d_in[9];
  const float* bv  = (const float*)d_in[10];
  const float* wp  = (const float*)d_in[11];
  const float* bp  = (const float*)d_in[12];
  const float* g2  = (const float*)d_in[13];
  const float* be2 = (const float*)d_in[14];
  const float* mu2 = (const float*)d_in[15];
  const float* va2 = (const float*)d_in[16];
  char* ws = (char*)d_ws;
  float* out = (float*)d_out;

  k0_fold<<<dim3(704), dim3(256), 0, stream>>>(g1, be1, mu1, va1, wq, bq, wk, bk,
                                               wv, bv, wp, bp, g2, be2, mu2, va2, ws);
  k1_qkv<<<dim3(2048), dim3(256), 0, stream>>>(x, ws);
  k2a_gram<<<dim3(512), dim3(256), 0, stream>>>(ws);
  k2b_softmax<<<dim3(8), dim3(256), 0, stream>>>(ws);
  k34_attn_proj<<<dim3(1024), dim3(256), 0, stream>>>(ws, out);
}